// Round 11
// baseline (829.424 us; speedup 1.0000x reference)
//
#include <hip/hip_runtime.h>
#include <cmath>

#define EPSV 1e-5f

typedef short bf16x8 __attribute__((ext_vector_type(8)));
typedef float f32x4 __attribute__((ext_vector_type(4)));
typedef unsigned int u32x2 __attribute__((ext_vector_type(2)));

__device__ __forceinline__ unsigned short f2bf(float f) {
  unsigned u = __float_as_uint(f);
  unsigned r = ((u >> 16) & 1u) + 0x7FFFu;   // RTNE
  return (unsigned short)((u + r) >> 16);
}

__device__ __forceinline__ unsigned cvt_pk_bf16(float lo, float hi) {
  unsigned d;
  asm("v_cvt_pk_bf16_f32 %0, %1, %2" : "=v"(d) : "v"(lo), "v"(hi));
  return d;
}

// ---------------- prep: weights fp32 -> bf16 K-TILE-MAJOR, + softmax(wmask) --------
__global__ void prep_conv(const float* __restrict__ w0, const float* __restrict__ w1,
                          const float* __restrict__ w2, unsigned short* __restrict__ w0b,
                          unsigned short* __restrict__ w1b, unsigned short* __restrict__ w2b,
                          const float* __restrict__ wmask, float* __restrict__ wm) {
  if (blockIdx.x >= 2368) {
    int g = (blockIdx.x - 2368) * 4 + (threadIdx.x >> 6);
    int lane = threadIdx.x & 63;
    const float* row = wmask + g * 144;
    float v0 = row[lane], v1 = row[lane + 64];
    float v2 = (lane < 16) ? row[lane + 128] : -1e30f;
    float m = fmaxf(fmaxf(v0, v1), v2);
    for (int off = 32; off; off >>= 1) m = fmaxf(m, __shfl_xor(m, off));
    float e0 = expf(v0 - m), e1 = expf(v1 - m), e2 = (lane < 16) ? expf(v2 - m) : 0.f;
    float s = e0 + e1 + e2;
    for (int off = 32; off; off >>= 1) s += __shfl_xor(s, off);
    float inv = 1.f / s;
    wm[g * 144 + lane] = e0 * inv;
    wm[g * 144 + lane + 64] = e1 * inv;
    if (lane < 16) wm[g * 144 + lane + 128] = e2 * inv;
    return;
  }
  int idx = blockIdx.x * 256 + threadIdx.x;
  if (idx < 512 * 608) {
    int o = idx / 608, k = idx - o * 608;
    float v = 0.f;
    if (k < 588) {
      int ph = (k >= 392) ? 2 : (k >= 196 ? 1 : 0);
      int q = k - ph * 196;
      v = w0[o * 588 + q * 3 + ph];
    }
    w0b[(k >> 5) * 16384 + o * 32 + (k & 31)] = f2bf(v);   // [19][512][32]
    return;
  }
  idx -= 512 * 608;
  if (idx < 384 * 512) {
    int o = idx / 512, k = idx - o * 512;
    w1b[(k >> 5) * 12288 + o * 32 + (k & 31)] = f2bf(w1[idx]);   // [16][384][32]
    return;
  }
  idx -= 384 * 512;
  if (idx < 256 * 384) {
    int o = idx / 384, k = idx - o * 384;
    w2b[(k >> 5) * 8192 + o * 32 + (k & 31)] = f2bf(w2[idx]);    // [12][256][32]
  }
}

// ---------------- fused main (template: MODE 0=real, 1=noB, 2=noAfLDS, 3=noMFMA) ---
// DIAGNOSTIC ROUND: MODE 0 is byte-for-byte the R6 best (248us), writes `out`.
// MODE 1/2/3 are single-phase ablations writing to workspace scratch (w0b region,
// rewritten by prep each iteration). Their counter dur_us isolates each phase's
// exposed cost. LDS map unchanged from R6.
#define LDS_XB 77824u

template<int MODE>
__launch_bounds__(512, 4)
__global__ void fused_main(const float* __restrict__ x, const float* __restrict__ b0,
                           const float* __restrict__ b1, const float* __restrict__ b2,
                           const unsigned short* __restrict__ w0b,
                           const unsigned short* __restrict__ w1b,
                           const unsigned short* __restrict__ w2b,
                           const float* __restrict__ wm, float* __restrict__ outp) {
  __shared__ __align__(16) char lds[79168];
  const int tid = threadIdx.x;
  const int wv = tid >> 6, lane = tid & 63;
  const int quad = lane >> 4, l15 = lane & 15;
  const int r0 = blockIdx.x * 64;
  const int bi0 = r0 / 144;
  const int boundary = (bi0 + 1) * 144;

  if (tid < 336) {
    int bb = (tid >= 168) ? 1 : 0;
    int e = tid - bb * 168;
    int gb = bi0 + bb;
    float v = 0.f;
    if (gb < 1024 && e != 167) v = x[gb * 168 + e];
    ((float*)(lds + LDS_XB))[bb * 168 + e] = v;
  }

  const int frow = tid >> 3, fu = tid & 7;
  int fh, fw;
  const float* fxb;
  {
    int fr = r0 + frow;
    int fb = (fr >= boundary) ? 1 : 0;
    int fp = fr - (bi0 + fb) * 144;
    fh = fp / 12;
    fw = fp - fh * 12;
    fxb = (const float*)(lds + LDS_XB) + fb * 168;
  }
  __syncthreads();

  // ---- generate ALL feat tiles ----
  {
    unsigned wbase = frow * 64u + (((fu >> 1) ^ ((frow >> 1) & 3)) * 16u) + (fu & 1) * 8u;
    for (int kt = 0; kt < 19; kt++) {
      int k0 = kt * 32 + fu * 4;
      unsigned lo = 0, hi = 0;
      if (k0 < 588) {
        int ph = (k0 >= 392) ? 2 : (k0 >= 196 ? 1 : 0);
        int q = k0 - ph * 196;
        int i = q / 14, j = q - i * 14;
        float f[4];
#pragma unroll
        for (int e = 0; e < 4; e++) {
          float a = fxb[i * 12 + fh], c = fxb[j * 12 + fw];
          if (ph == 0) f[e] = c - a;
          else {
            float rr = __builtin_amdgcn_rcpf(a + c + EPSV);
            f[e] = (ph == 1) ? (c - a) * rr : c * rr;
          }
          if (++j == 14) { j = 0; i++; }
        }
        lo = cvt_pk_bf16(f[0], f[1]);
        hi = cvt_pk_bf16(f[2], f[3]);
      }
      *(u32x2*)(lds + kt * 4096u + wbase) = u32x2{lo, hi};
    }
  }
  __syncthreads();

  // =================== Layer 0 ===================
  {
    f32x4 acc[4][4];
#pragma unroll
    for (int ct = 0; ct < 4; ct++) {
      f32x4 bias = *(const f32x4*)(b0 + wv * 64 + ct * 16 + quad * 4);
#pragma unroll
      for (int rt = 0; rt < 4; rt++) acc[rt][ct] = bias;
    }

    const char* wb = (const char*)w0b + (unsigned)(wv * 64 + l15) * 64u + quad * 16u;
    const unsigned afb = l15 * 64u + ((quad ^ ((l15 >> 1) & 3)) * 16u);

#pragma unroll 1
    for (int kt = 0; kt < 19; kt++) {
      bf16x8 bfr[4], af[4];
      if constexpr (MODE == 1) {
#pragma unroll
        for (int ct = 0; ct < 4; ct++) bfr[ct] = bf16x8{0, 0, 0, 0, 0, 0, 0, 0};
      } else {
#pragma unroll
        for (int ct = 0; ct < 4; ct++)
          bfr[ct] = *(const bf16x8*)(wb + ct * 1024);
      }
      if constexpr (MODE == 2) {
#pragma unroll
        for (int rt = 0; rt < 4; rt++) af[rt] = bf16x8{0, 0, 0, 0, 0, 0, 0, 0};
      } else {
#pragma unroll
        for (int rt = 0; rt < 4; rt++)
          af[rt] = *(const bf16x8*)(lds + kt * 4096u + afb + rt * 1024u);
      }
      if constexpr (MODE == 3) {
        asm volatile("" :: "v"(bfr[0]), "v"(bfr[1]), "v"(bfr[2]), "v"(bfr[3]),
                          "v"(af[0]), "v"(af[1]), "v"(af[2]), "v"(af[3]));
      } else {
        __builtin_amdgcn_s_setprio(1);
#pragma unroll
        for (int rt = 0; rt < 4; rt++)
#pragma unroll
          for (int ct = 0; ct < 4; ct++)
            acc[rt][ct] = __builtin_amdgcn_mfma_f32_16x16x32_bf16(bfr[ct], af[rt], acc[rt][ct], 0, 0, 0);
        __builtin_amdgcn_s_setprio(0);
      }
      wb += 32768;
    }
    __syncthreads();
#pragma unroll
    for (int ct = 0; ct < 4; ct++) {
      int nb = wv * 64 + ct * 16 + quad * 4;
      int kb = nb >> 3;
      unsigned off = (nb & 7) * 2;
#pragma unroll
      for (int rt = 0; rt < 4; rt++) {
        int m = rt * 16 + l15;
        f32x4 v = acc[rt][ct];
        unsigned lo = cvt_pk_bf16(fmaxf(v[0], 0.f), fmaxf(v[1], 0.f));
        unsigned hi = cvt_pk_bf16(fmaxf(v[2], 0.f), fmaxf(v[3], 0.f));
        *(u32x2*)(lds + m * 1024u + ((kb + m) & 63) * 16u + off) = u32x2{lo, hi};
      }
    }
  }
  __syncthreads();

  // =================== Layer 1 ===================
  {
    f32x4 acc[4][3];
#pragma unroll
    for (int ct = 0; ct < 3; ct++) {
      f32x4 bias = *(const f32x4*)(b1 + wv * 48 + ct * 16 + quad * 4);
#pragma unroll
      for (int rt = 0; rt < 4; rt++) acc[rt][ct] = bias;
    }

    const char* wb = (const char*)w1b + (unsigned)(wv * 48 + l15) * 64u + quad * 16u;

#pragma unroll 1
    for (int kt = 0; kt < 16; kt++) {
      bf16x8 bfr[3], af[4];
      if constexpr (MODE == 1) {
#pragma unroll
        for (int ct = 0; ct < 3; ct++) bfr[ct] = bf16x8{0, 0, 0, 0, 0, 0, 0, 0};
      } else {
#pragma unroll
        for (int ct = 0; ct < 3; ct++)
          bfr[ct] = *(const bf16x8*)(wb + ct * 1024);
      }
      if constexpr (MODE == 2) {
#pragma unroll
        for (int rt = 0; rt < 4; rt++) af[rt] = bf16x8{0, 0, 0, 0, 0, 0, 0, 0};
      } else {
#pragma unroll
        for (int rt = 0; rt < 4; rt++) {
          int m = rt * 16 + l15;
          af[rt] = *(const bf16x8*)(lds + m * 1024u + (((kt * 4 + quad) + m) & 63) * 16u);
        }
      }
      if constexpr (MODE == 3) {
        asm volatile("" :: "v"(bfr[0]), "v"(bfr[1]), "v"(bfr[2]),
                          "v"(af[0]), "v"(af[1]), "v"(af[2]), "v"(af[3]));
      } else {
        __builtin_amdgcn_s_setprio(1);
#pragma unroll
        for (int rt = 0; rt < 4; rt++)
#pragma unroll
          for (int ct = 0; ct < 3; ct++)
            acc[rt][ct] = __builtin_amdgcn_mfma_f32_16x16x32_bf16(bfr[ct], af[rt], acc[rt][ct], 0, 0, 0);
        __builtin_amdgcn_s_setprio(0);
      }
      wb += 24576;
    }
    __syncthreads();
#pragma unroll
    for (int ct = 0; ct < 3; ct++) {
      int nb = wv * 48 + ct * 16 + quad * 4;
      int kb = nb >> 3;
      unsigned off = (nb & 7) * 2;
#pragma unroll
      for (int rt = 0; rt < 4; rt++) {
        int m = rt * 16 + l15;
        int s = kb + m;
        if (s >= 48) s -= 48;
        if (s >= 48) s -= 48;
        f32x4 v = acc[rt][ct];
        unsigned lo = cvt_pk_bf16(fmaxf(v[0], 0.f), fmaxf(v[1], 0.f));
        unsigned hi = cvt_pk_bf16(fmaxf(v[2], 0.f), fmaxf(v[3], 0.f));
        *(u32x2*)(lds + m * 768u + s * 16u + off) = u32x2{lo, hi};
      }
    }
  }
  __syncthreads();

  // =================== Layer 2 ===================
  {
    f32x4 acc[4][2];
#pragma unroll
    for (int ct = 0; ct < 2; ct++) {
      float bias = b2[wv * 32 + ct * 16 + l15];
#pragma unroll
      for (int rt = 0; rt < 4; rt++) acc[rt][ct] = f32x4{bias, bias, bias, bias};
    }

    const char* wb = (const char*)w2b + (unsigned)(wv * 32 + l15) * 64u + quad * 16u;

#pragma unroll 1
    for (int kt = 0; kt < 12; kt++) {
      bf16x8 bfr[2], af[4];
      if constexpr (MODE == 1) {
#pragma unroll
        for (int ct = 0; ct < 2; ct++) bfr[ct] = bf16x8{0, 0, 0, 0, 0, 0, 0, 0};
      } else {
#pragma unroll
        for (int ct = 0; ct < 2; ct++)
          bfr[ct] = *(const bf16x8*)(wb + ct * 1024);
      }
      if constexpr (MODE == 2) {
#pragma unroll
        for (int rt = 0; rt < 4; rt++) af[rt] = bf16x8{0, 0, 0, 0, 0, 0, 0, 0};
      } else {
#pragma unroll
        for (int rt = 0; rt < 4; rt++) {
          int m = rt * 16 + l15;
          int s = (kt * 4 + quad) + m;
          if (s >= 48) s -= 48;
          if (s >= 48) s -= 48;
          af[rt] = *(const bf16x8*)(lds + m * 768u + s * 16u);
        }
      }
      if constexpr (MODE == 3) {
        asm volatile("" :: "v"(bfr[0]), "v"(bfr[1]),
                          "v"(af[0]), "v"(af[1]), "v"(af[2]), "v"(af[3]));
      } else {
        __builtin_amdgcn_s_setprio(1);
#pragma unroll
        for (int rt = 0; rt < 4; rt++)
#pragma unroll
          for (int ct = 0; ct < 2; ct++)
            acc[rt][ct] = __builtin_amdgcn_mfma_f32_16x16x32_bf16(af[rt], bfr[ct], acc[rt][ct], 0, 0, 0);
        __builtin_amdgcn_s_setprio(0);
      }
      wb += 16384;
    }

#pragma unroll
    for (int ct = 0; ct < 2; ct++) {
      int col = wv * 32 + ct * 16 + l15;
      const float* wmg = wm + (col >> 4) * 144;
      float s0 = 0.f, s1 = 0.f;
#pragma unroll
      for (int rt = 0; rt < 4; rt++)
#pragma unroll
        for (int vi = 0; vi < 4; vi++) {
          int r = r0 + rt * 16 + quad * 4 + vi;
          float v = fmaxf(acc[rt][ct][vi], 0.f);
          if (r < boundary) s0 += v * wmg[r - bi0 * 144];
          else              s1 += v * wmg[r - boundary];
        }
      s0 += __shfl_xor(s0, 16); s0 += __shfl_xor(s0, 32);
      s1 += __shfl_xor(s1, 16); s1 += __shfl_xor(s1, 32);
      if (quad == 0) {
        atomicAdd(outp + bi0 * 256 + col, s0);
        if (boundary < r0 + 64) atomicAdd(outp + (bi0 + 1) * 256 + col, s1);
      }
    }
  }
}

extern "C" void kernel_launch(void* const* d_in, const int* in_sizes, int n_in,
                              void* d_out, int out_size, void* d_ws, size_t ws_size,
                              hipStream_t stream) {
  (void)in_sizes; (void)n_in; (void)ws_size;
  const float* x     = (const float*)d_in[0];
  const float* w0    = (const float*)d_in[1];
  const float* b0    = (const float*)d_in[2];
  const float* w1    = (const float*)d_in[3];
  const float* b1    = (const float*)d_in[4];
  const float* w2    = (const float*)d_in[5];
  const float* b2    = (const float*)d_in[6];
  const float* wmask = (const float*)d_in[7];
  float* out = (float*)d_out;
  char* ws = (char*)d_ws;
  float* wm = (float*)ws;                                        // 16*144*4 = 9216
  unsigned short* w0b = (unsigned short*)(ws + 9216);            // 512*608*2 = 622592
  unsigned short* w1b = (unsigned short*)(ws + 9216 + 622592);   // 384*512*2 = 393216
  unsigned short* w2b = (unsigned short*)(ws + 9216 + 622592 + 393216);  // 256*384*2
  // diagnostic scratch: overlays w0b/w1b/w2b (1 MB of atomics land inside the
  // 1.19 MB prep region, which prep_conv fully rewrites every iteration).
  float* scratch = (float*)(ws + 9216);

  hipMemsetAsync(d_out, 0, (size_t)out_size * sizeof(float), stream);
  prep_conv<<<2372, 256, 0, stream>>>(w0, w1, w2, w0b, w1b, w2b, wmask, wm);
  fused_main<0><<<2304, 512, 0, stream>>>(x, b0, b1, b2, w0b, w1b, w2b, wm, out);
  // ---- diagnostics (results discarded; weights they read may be mid-scribble,
  //      which affects values only, not timing) ----
  fused_main<1><<<2304, 512, 0, stream>>>(x, b0, b1, b2, w0b, w1b, w2b, wm, scratch);
  fused_main<2><<<2304, 512, 0, stream>>>(x, b0, b1, b2, w0b, w1b, w2b, wm, scratch);
  fused_main<3><<<2304, 512, 0, stream>>>(x, b0, b1, b2, w0b, w1b, w2b, wm, scratch);
}

// Round 12
// 248.236 us; speedup vs baseline: 3.3413x; 3.3413x over previous
//
#include <hip/hip_runtime.h>
#include <cmath>

#define EPSV 1e-5f

typedef short bf16x8 __attribute__((ext_vector_type(8)));
typedef float f32x4 __attribute__((ext_vector_type(4)));
typedef unsigned int u32x2 __attribute__((ext_vector_type(2)));

__device__ __forceinline__ unsigned short f2bf(float f) {
  unsigned u = __float_as_uint(f);
  unsigned r = ((u >> 16) & 1u) + 0x7FFFu;   // RTNE
  return (unsigned short)((u + r) >> 16);
}

__device__ __forceinline__ unsigned cvt_pk_bf16(float lo, float hi) {
  unsigned d;
  asm("v_cvt_pk_bf16_f32 %0, %1, %2" : "=v"(d) : "v"(lo), "v"(hi));
  return d;
}

// ---------------- prep: weights fp32 -> bf16 K-TILE-MAJOR, + softmax(wmask) --------
// L0 ALGEBRAIC COLLAPSE: feat phase di = xj - xi is LINEAR in the 28 inputs, so
// sum_{i,j} w*(xj[j]-xi[i]) = sum_j colsum_j*xj[j] - sum_i rowsum_i*xi[i].
// New L0 K layout (448 = 14 tiles of 32):
//   k in [0,196)   : di/s ratio   (orig phase 1), q = k
//   k in [196,392) : xj/s ratio   (orig phase 2), q = k-196
//   k in [392,406) : xi[t]        weight = -rowsum_t
//   k in [406,420) : xj[t-14]     weight = +colsum_{t-14}
//   k in [420,448) : zero pad
// Layout per layer: w[kt][n][32 k] (one contiguous 1KB segment per wave fragment).
__global__ void prep_conv(const float* __restrict__ w0, const float* __restrict__ w1,
                          const float* __restrict__ w2, unsigned short* __restrict__ w0b,
                          unsigned short* __restrict__ w1b, unsigned short* __restrict__ w2b,
                          const float* __restrict__ wmask, float* __restrict__ wm) {
  if (blockIdx.x >= 2048) {
    int g = (blockIdx.x - 2048) * 4 + (threadIdx.x >> 6);
    int lane = threadIdx.x & 63;
    const float* row = wmask + g * 144;
    float v0 = row[lane], v1 = row[lane + 64];
    float v2 = (lane < 16) ? row[lane + 128] : -1e30f;
    float m = fmaxf(fmaxf(v0, v1), v2);
    for (int off = 32; off; off >>= 1) m = fmaxf(m, __shfl_xor(m, off));
    float e0 = expf(v0 - m), e1 = expf(v1 - m), e2 = (lane < 16) ? expf(v2 - m) : 0.f;
    float s = e0 + e1 + e2;
    for (int off = 32; off; off >>= 1) s += __shfl_xor(s, off);
    float inv = 1.f / s;
    wm[g * 144 + lane] = e0 * inv;
    wm[g * 144 + lane + 64] = e1 * inv;
    if (lane < 16) wm[g * 144 + lane + 128] = e2 * inv;
    return;
  }
  int idx = blockIdx.x * 256 + threadIdx.x;
  if (idx < 512 * 448) {
    int o = idx / 448, k = idx - o * 448;
    float v = 0.f;
    if (k < 392) {
      int ph = (k >= 196) ? 1 : 0;
      int q = k - ph * 196;
      v = w0[o * 588 + q * 3 + ph + 1];          // orig phases 1 (di/s), 2 (xj/s)
    } else if (k < 420) {
      int t = k - 392;
      float s = 0.f;
      if (t < 14) {                               // -rowsum_t (xi coefficient)
        for (int j = 0; j < 14; j++) s += w0[o * 588 + (t * 14 + j) * 3];
        v = -s;
      } else {                                    // +colsum_{t-14} (xj coefficient)
        int j = t - 14;
        for (int i = 0; i < 14; i++) s += w0[o * 588 + (i * 14 + j) * 3];
        v = s;
      }
    }
    w0b[(k >> 5) * 16384 + o * 32 + (k & 31)] = f2bf(v);   // [14][512][32]
    return;
  }
  idx -= 512 * 448;
  if (idx < 384 * 512) {
    int o = idx / 512, k = idx - o * 512;
    w1b[(k >> 5) * 12288 + o * 32 + (k & 31)] = f2bf(w1[idx]);   // [16][384][32]
    return;
  }
  idx -= 384 * 512;
  if (idx < 256 * 384) {
    int o = idx / 384, k = idx - o * 384;
    w2b[(k >> 5) * 8192 + o * 32 + (k & 31)] = f2bf(w2[idx]);    // [12][256][32]
  }
}

// ---------------- fused main ------------------------------------------------------
// R12 = R6 (best, 245us) with L0 K reduced 608 -> 448 (19 -> 14 k-tiles) via the
// linear-phase collapse. Execution is near-serial (R11 ablations: each phase's
// removal saves only its own share), so time should scale with work removed.
// LDS map (66.9 KB -> 2 blocks/CU):
//  FT : [0, 57344)      feat 14 tiles x (64 rows x 64B), XOR chunk-swizzle
//                       h0 (64 KB, [0,65536)) then h1 (48 KB) overlay this region
//  XB : [65536, 66880)  x cache: 2 batches x 168 f32 (elem 167 zeroed)
#define LDS_XB 65536u

__launch_bounds__(512, 4)
__global__ void fused_main(const float* __restrict__ x, const float* __restrict__ b0,
                           const float* __restrict__ b1, const float* __restrict__ b2,
                           const unsigned short* __restrict__ w0b,
                           const unsigned short* __restrict__ w1b,
                           const unsigned short* __restrict__ w2b,
                           const float* __restrict__ wm, float* __restrict__ out) {
  __shared__ __align__(16) char lds[66880];
  const int tid = threadIdx.x;
  const int wv = tid >> 6, lane = tid & 63;
  const int quad = lane >> 4, l15 = lane & 15;
  const int r0 = blockIdx.x * 64;
  const int bi0 = r0 / 144;
  const int boundary = (bi0 + 1) * 144;

  // ---- x cache: the <=2 batch rows this block touches (1344 B), x[:,167]=0 ----
  if (tid < 336) {
    int bb = (tid >= 168) ? 1 : 0;
    int e = tid - bb * 168;
    int gb = bi0 + bb;
    float v = 0.f;
    if (gb < 1024 && e != 167) v = x[gb * 168 + e];
    ((float*)(lds + LDS_XB))[bb * 168 + e] = v;
  }

  // per-thread feat-gen constants
  const int frow = tid >> 3, fu = tid & 7;
  int fh, fw;
  const float* fxb;
  {
    int fr = r0 + frow;
    int fb = (fr >= boundary) ? 1 : 0;
    int fp = fr - (bi0 + fb) * 144;
    fh = fp / 12;
    fw = fp - fh * 12;
    fxb = (const float*)(lds + LDS_XB) + fb * 168;
  }
  __syncthreads();

  // ---- generate ALL feat tiles (new 448-K layout; 14 x 32-k tiles) ----
  {
    unsigned wbase = frow * 64u + (((fu >> 1) ^ ((frow >> 1) & 3)) * 16u) + (fu & 1) * 8u;
    for (int kt = 0; kt < 14; kt++) {
      int k0 = kt * 32 + fu * 4;
      unsigned lo = 0, hi = 0;
      if (k0 < 392) {
        // ratio phases; 196 ≡ 0 (mod 4) => all 4 elems share one phase
        int ph = (k0 >= 196) ? 1 : 0;
        int q = k0 - ph * 196;
        int i = q / 14, j = q - i * 14;
        float f[4];
#pragma unroll
        for (int e = 0; e < 4; e++) {
          float a = fxb[i * 12 + fh], c = fxb[j * 12 + fw];
          float rr = __builtin_amdgcn_rcpf(a + c + EPSV);
          f[e] = (ph == 0) ? (c - a) * rr : c * rr;
          if (++j == 14) { j = 0; i++; }
        }
        lo = cvt_pk_bf16(f[0], f[1]);
        hi = cvt_pk_bf16(f[2], f[3]);
      } else if (k0 < 420) {
        // linear features: xi[t] (t<14) then xj[t-14]
        float f[4];
#pragma unroll
        for (int e = 0; e < 4; e++) {
          int t = k0 - 392 + e;
          f[e] = (t < 14) ? fxb[t * 12 + fh] : fxb[(t - 14) * 12 + fw];
        }
        lo = cvt_pk_bf16(f[0], f[1]);
        hi = cvt_pk_bf16(f[2], f[3]);
      }
      *(u32x2*)(lds + kt * 4096u + wbase) = u32x2{lo, hi};
    }
  }
  __syncthreads();

  // =================== Layer 0 : feat(448) -> 512 (swapped operands) ===============
  {
    f32x4 acc[4][4];
#pragma unroll
    for (int ct = 0; ct < 4; ct++) {
      f32x4 bias = *(const f32x4*)(b0 + wv * 64 + ct * 16 + quad * 4);
#pragma unroll
      for (int rt = 0; rt < 4; rt++) acc[rt][ct] = bias;
    }

    // k-tile-major: wave's load for ct = ONE contiguous 1KB segment.
    const char* wb = (const char*)w0b + (unsigned)(wv * 64 + l15) * 64u + quad * 16u;
    const unsigned afb = l15 * 64u + ((quad ^ ((l15 >> 1) & 3)) * 16u);

#pragma unroll 1
    for (int kt = 0; kt < 14; kt++) {
      bf16x8 bfr[4], af[4];
#pragma unroll
      for (int ct = 0; ct < 4; ct++)
        bfr[ct] = *(const bf16x8*)(wb + ct * 1024);   // imm offsets, coalesced
#pragma unroll
      for (int rt = 0; rt < 4; rt++)
        af[rt] = *(const bf16x8*)(lds + kt * 4096u + afb + rt * 1024u);
      __builtin_amdgcn_s_setprio(1);
#pragma unroll
      for (int rt = 0; rt < 4; rt++)
#pragma unroll
        for (int ct = 0; ct < 4; ct++)
          acc[rt][ct] = __builtin_amdgcn_mfma_f32_16x16x32_bf16(bfr[ct], af[rt], acc[rt][ct], 0, 0, 0);
      __builtin_amdgcn_s_setprio(0);
      wb += 32768;   // next k-tile
    }
    __syncthreads();   // all waves done reading feat; h0 overlays it
    // epilogue: relu -> bf16 h0 at base 0 (chunk-rotate swizzle), packed b64 writes
#pragma unroll
    for (int ct = 0; ct < 4; ct++) {
      int nb = wv * 64 + ct * 16 + quad * 4;
      int kb = nb >> 3;
      unsigned off = (nb & 7) * 2;
#pragma unroll
      for (int rt = 0; rt < 4; rt++) {
        int m = rt * 16 + l15;
        f32x4 v = acc[rt][ct];
        unsigned lo = cvt_pk_bf16(fmaxf(v[0], 0.f), fmaxf(v[1], 0.f));
        unsigned hi = cvt_pk_bf16(fmaxf(v[2], 0.f), fmaxf(v[3], 0.f));
        *(u32x2*)(lds + m * 1024u + ((kb + m) & 63) * 16u + off) = u32x2{lo, hi};
      }
    }
  }
  __syncthreads();   // h0 visible

  // =================== Layer 1 : 512 -> 384 (swapped operands, barrier-free) =======
  {
    f32x4 acc[4][3];
#pragma unroll
    for (int ct = 0; ct < 3; ct++) {
      f32x4 bias = *(const f32x4*)(b1 + wv * 48 + ct * 16 + quad * 4);
#pragma unroll
      for (int rt = 0; rt < 4; rt++) acc[rt][ct] = bias;
    }

    const char* wb = (const char*)w1b + (unsigned)(wv * 48 + l15) * 64u + quad * 16u;

#pragma unroll 1
    for (int kt = 0; kt < 16; kt++) {
      bf16x8 bfr[3], af[4];
#pragma unroll
      for (int ct = 0; ct < 3; ct++)
        bfr[ct] = *(const bf16x8*)(wb + ct * 1024);
#pragma unroll
      for (int rt = 0; rt < 4; rt++) {
        int m = rt * 16 + l15;
        af[rt] = *(const bf16x8*)(lds + m * 1024u + (((kt * 4 + quad) + m) & 63) * 16u);
      }
      __builtin_amdgcn_s_setprio(1);
#pragma unroll
      for (int rt = 0; rt < 4; rt++)
#pragma unroll
        for (int ct = 0; ct < 3; ct++)
          acc[rt][ct] = __builtin_amdgcn_mfma_f32_16x16x32_bf16(bfr[ct], af[rt], acc[rt][ct], 0, 0, 0);
      __builtin_amdgcn_s_setprio(0);
      wb += 24576;
    }
    __syncthreads();   // all waves done READING h0 before h1 overwrites the region
    // epilogue -> h1 at base 0 (48 chunks/row, rotate mod 48), packed b64 writes
#pragma unroll
    for (int ct = 0; ct < 3; ct++) {
      int nb = wv * 48 + ct * 16 + quad * 4;
      int kb = nb >> 3;
      unsigned off = (nb & 7) * 2;
#pragma unroll
      for (int rt = 0; rt < 4; rt++) {
        int m = rt * 16 + l15;
        int s = kb + m;
        if (s >= 48) s -= 48;
        if (s >= 48) s -= 48;
        f32x4 v = acc[rt][ct];
        unsigned lo = cvt_pk_bf16(fmaxf(v[0], 0.f), fmaxf(v[1], 0.f));
        unsigned hi = cvt_pk_bf16(fmaxf(v[2], 0.f), fmaxf(v[3], 0.f));
        *(u32x2*)(lds + m * 768u + s * 16u + off) = u32x2{lo, hi};
      }
    }
  }
  __syncthreads();   // h1 visible

  // =================== Layer 2 : 384 -> 256, fused reduction (barrier-free) ========
  // Original operand order: lane owns col => row-reduction via 2 shfls.
  {
    f32x4 acc[4][2];
#pragma unroll
    for (int ct = 0; ct < 2; ct++) {
      float bias = b2[wv * 32 + ct * 16 + l15];
#pragma unroll
      for (int rt = 0; rt < 4; rt++) acc[rt][ct] = f32x4{bias, bias, bias, bias};
    }

    const char* wb = (const char*)w2b + (unsigned)(wv * 32 + l15) * 64u + quad * 16u;

#pragma unroll 1
    for (int kt = 0; kt < 12; kt++) {
      bf16x8 bfr[2], af[4];
#pragma unroll
      for (int ct = 0; ct < 2; ct++)
        bfr[ct] = *(const bf16x8*)(wb + ct * 1024);
#pragma unroll
      for (int rt = 0; rt < 4; rt++) {
        int m = rt * 16 + l15;
        int s = (kt * 4 + quad) + m;
        if (s >= 48) s -= 48;
        if (s >= 48) s -= 48;
        af[rt] = *(const bf16x8*)(lds + m * 768u + s * 16u);
      }
      __builtin_amdgcn_s_setprio(1);
#pragma unroll
      for (int rt = 0; rt < 4; rt++)
#pragma unroll
        for (int ct = 0; ct < 2; ct++)
          acc[rt][ct] = __builtin_amdgcn_mfma_f32_16x16x32_bf16(af[rt], bfr[ct], acc[rt][ct], 0, 0, 0);
      __builtin_amdgcn_s_setprio(0);
      wb += 16384;
    }

    // epilogue: relu(h2) * softmax-wm, reduce over rows, atomicAdd into out
#pragma unroll
    for (int ct = 0; ct < 2; ct++) {
      int col = wv * 32 + ct * 16 + l15;
      const float* wmg = wm + (col >> 4) * 144;
      float s0 = 0.f, s1 = 0.f;
#pragma unroll
      for (int rt = 0; rt < 4; rt++)
#pragma unroll
        for (int vi = 0; vi < 4; vi++) {
          int r = r0 + rt * 16 + quad * 4 + vi;
          float v = fmaxf(acc[rt][ct][vi], 0.f);
          if (r < boundary) s0 += v * wmg[r - bi0 * 144];
          else              s1 += v * wmg[r - boundary];
        }
      s0 += __shfl_xor(s0, 16); s0 += __shfl_xor(s0, 32);
      s1 += __shfl_xor(s1, 16); s1 += __shfl_xor(s1, 32);
      if (quad == 0) {
        atomicAdd(out + bi0 * 256 + col, s0);
        if (boundary < r0 + 64) atomicAdd(out + (bi0 + 1) * 256 + col, s1);
      }
    }
  }
}

extern "C" void kernel_launch(void* const* d_in, const int* in_sizes, int n_in,
                              void* d_out, int out_size, void* d_ws, size_t ws_size,
                              hipStream_t stream) {
  (void)in_sizes; (void)n_in; (void)ws_size;
  const float* x     = (const float*)d_in[0];
  const float* w0    = (const float*)d_in[1];
  const float* b0    = (const float*)d_in[2];
  const float* w1    = (const float*)d_in[3];
  const float* b1    = (const float*)d_in[4];
  const float* w2    = (const float*)d_in[5];
  const float* b2    = (const float*)d_in[6];
  const float* wmask = (const float*)d_in[7];
  float* out = (float*)d_out;
  char* ws = (char*)d_ws;
  float* wm = (float*)ws;                                        // 16*144*4 = 9216
  unsigned short* w0b = (unsigned short*)(ws + 9216);            // 512*448*2 = 458752
  unsigned short* w1b = (unsigned short*)(ws + 9216 + 458752);   // 384*512*2 = 393216
  unsigned short* w2b = (unsigned short*)(ws + 9216 + 458752 + 393216);  // 256*384*2

  hipMemsetAsync(d_out, 0, (size_t)out_size * sizeof(float), stream);
  prep_conv<<<2052, 256, 0, stream>>>(w0, w1, w2, w0b, w1b, w2b, wmask, wm);
  fused_main<<<2304, 512, 0, stream>>>(x, b0, b1, b2, w0b, w1b, w2b, wm, out);
}

// Round 13
// 238.109 us; speedup vs baseline: 3.4834x; 1.0425x over previous
//
#include <hip/hip_runtime.h>
#include <cmath>

#define EPSV 1e-5f

typedef short bf16x8 __attribute__((ext_vector_type(8)));
typedef float f32x4 __attribute__((ext_vector_type(4)));
typedef unsigned int u32x2 __attribute__((ext_vector_type(2)));

__device__ __forceinline__ unsigned short f2bf(float f) {
  unsigned u = __float_as_uint(f);
  unsigned r = ((u >> 16) & 1u) + 0x7FFFu;   // RTNE
  return (unsigned short)((u + r) >> 16);
}

__device__ __forceinline__ unsigned cvt_pk_bf16(float lo, float hi) {
  unsigned d;
  asm("v_cvt_pk_bf16_f32 %0, %1, %2" : "=v"(d) : "v"(lo), "v"(hi));
  return d;
}

// ---------------- prep: weights fp32 -> bf16 K-TILE-MAJOR, + softmax + out-zero ----
// L0 K layout (448 = 14 tiles of 32), linear-phase collapse (see R12):
//   [0,196) di/s ; [196,392) xj/s ; [392,406) xi (w=-rowsum) ; [406,420) xj (w=+colsum)
//   [420,448) zero pad.  Per layer: w[kt][n][32 k] (1KB contiguous per wave fragment).
// Blocks < 1024 also zero one 256-float slice of `out` (replaces hipMemsetAsync).
__global__ void prep_conv(const float* __restrict__ w0, const float* __restrict__ w1,
                          const float* __restrict__ w2, unsigned short* __restrict__ w0b,
                          unsigned short* __restrict__ w1b, unsigned short* __restrict__ w2b,
                          const float* __restrict__ wmask, float* __restrict__ wm,
                          float* __restrict__ out) {
  if (blockIdx.x < 1024) out[blockIdx.x * 256 + threadIdx.x] = 0.f;
  if (blockIdx.x >= 2048) {
    int g = (blockIdx.x - 2048) * 4 + (threadIdx.x >> 6);
    int lane = threadIdx.x & 63;
    const float* row = wmask + g * 144;
    float v0 = row[lane], v1 = row[lane + 64];
    float v2 = (lane < 16) ? row[lane + 128] : -1e30f;
    float m = fmaxf(fmaxf(v0, v1), v2);
    for (int off = 32; off; off >>= 1) m = fmaxf(m, __shfl_xor(m, off));
    float e0 = expf(v0 - m), e1 = expf(v1 - m), e2 = (lane < 16) ? expf(v2 - m) : 0.f;
    float s = e0 + e1 + e2;
    for (int off = 32; off; off >>= 1) s += __shfl_xor(s, off);
    float inv = 1.f / s;
    wm[g * 144 + lane] = e0 * inv;
    wm[g * 144 + lane + 64] = e1 * inv;
    if (lane < 16) wm[g * 144 + lane + 128] = e2 * inv;
    return;
  }
  int idx = blockIdx.x * 256 + threadIdx.x;
  if (idx < 512 * 448) {
    int o = idx / 448, k = idx - o * 448;
    float v = 0.f;
    if (k < 392) {
      int ph = (k >= 196) ? 1 : 0;
      int q = k - ph * 196;
      v = w0[o * 588 + q * 3 + ph + 1];          // orig phases 1 (di/s), 2 (xj/s)
    } else if (k < 420) {
      int t = k - 392;
      float s = 0.f;
      if (t < 14) {                               // -rowsum_t (xi coefficient)
        for (int j = 0; j < 14; j++) s += w0[o * 588 + (t * 14 + j) * 3];
        v = -s;
      } else {                                    // +colsum_{t-14} (xj coefficient)
        int j = t - 14;
        for (int i = 0; i < 14; i++) s += w0[o * 588 + (i * 14 + j) * 3];
        v = s;
      }
    }
    w0b[(k >> 5) * 16384 + o * 32 + (k & 31)] = f2bf(v);   // [14][512][32]
    return;
  }
  idx -= 512 * 448;
  if (idx < 384 * 512) {
    int o = idx / 512, k = idx - o * 512;
    w1b[(k >> 5) * 12288 + o * 32 + (k & 31)] = f2bf(w1[idx]);   // [16][384][32]
    return;
  }
  idx -= 384 * 512;
  if (idx < 256 * 384) {
    int o = idx / 384, k = idx - o * 384;
    w2b[(k >> 5) * 8192 + o * 32 + (k & 31)] = f2bf(w2[idx]);    // [12][256][32]
  }
}

// ---------------- fused main ------------------------------------------------------
// R13 = R12 (best, 208us) + featgen dedup: one pass per PAIR computes both ratio
// phases from a single rcp (writes k=q and k=q+196), halving featgen rcps and LDS
// x-reads; separate small linear + zero passes. Plus memset folded into prep.
// LDS map (66.9 KB -> 2 blocks/CU):
//  FT : [0, 57344)      feat 14 tiles x (64 rows x 64B), XOR chunk-swizzle
//                       h0 (64 KB, [0,65536)) then h1 (48 KB) overlay this region
//  XB : [65536, 66880)  x cache: 2 batches x 168 f32 (elem 167 zeroed)
#define LDS_XB 65536u

__launch_bounds__(512, 4)
__global__ void fused_main(const float* __restrict__ x, const float* __restrict__ b0,
                           const float* __restrict__ b1, const float* __restrict__ b2,
                           const unsigned short* __restrict__ w0b,
                           const unsigned short* __restrict__ w1b,
                           const unsigned short* __restrict__ w2b,
                           const float* __restrict__ wm, float* __restrict__ out) {
  __shared__ __align__(16) char lds[66880];
  const int tid = threadIdx.x;
  const int wv = tid >> 6, lane = tid & 63;
  const int quad = lane >> 4, l15 = lane & 15;
  const int r0 = blockIdx.x * 64;
  const int bi0 = r0 / 144;
  const int boundary = (bi0 + 1) * 144;

  // ---- x cache: the <=2 batch rows this block touches (1344 B), x[:,167]=0 ----
  if (tid < 336) {
    int bb = (tid >= 168) ? 1 : 0;
    int e = tid - bb * 168;
    int gb = bi0 + bb;
    float v = 0.f;
    if (gb < 1024 && e != 167) v = x[gb * 168 + e];
    ((float*)(lds + LDS_XB))[bb * 168 + e] = v;
  }

  // per-thread feat-gen constants
  const int frow = tid >> 3, fu = tid & 7;
  int fh, fw;
  const float* fxb;
  {
    int fr = r0 + frow;
    int fb = (fr >= boundary) ? 1 : 0;
    int fp = fr - (bi0 + fb) * 144;
    fh = fp / 12;
    fw = fp - fh * 12;
    fxb = (const float*)(lds + LDS_XB) + fb * 168;
  }
  __syncthreads();

  // ---- generate ALL feat tiles (448-K layout; 14 x 32-k tiles) -------------------
  // Dedup pass: pair-quad q0 = kt*32 + fu*4 (kt 0..6, q0<196) computes BOTH
  // (di/s, write k=q0 in tile kt) and (xj/s, write k=q0+196 in tile kt+6(+1)).
  {
    // swizzled byte offset within a tile for elem-group g (g = k&31 >> 2):
    //   byte(g) = frow*64 + ((g>>1)^((frow>>1)&3))*16 + (g&1)*8
    const unsigned rsw = ((frow >> 1) & 3);
    auto wboff = [&](int g) -> unsigned {
      return (unsigned)frow * 64u + (((unsigned)(g >> 1) ^ rsw) * 16u) + (unsigned)(g & 1) * 8u;
    };
    const unsigned wb0 = wboff(fu);                 // phase-0 target (tile kt)
    const int fu2 = (fu + 1) & 7;
    const unsigned wb1 = wboff(fu2);                // phase-1 partner target
    const unsigned t1delta = (6 + (fu == 7 ? 1 : 0)) * 4096u;
#pragma unroll 1
    for (int kt = 0; kt < 7; kt++) {
      int q0 = kt * 32 + fu * 4;
      if (q0 < 196) {
        int i = q0 / 14, j = q0 - i * 14;
        float f0[4], f1[4];
#pragma unroll
        for (int e = 0; e < 4; e++) {
          float a = fxb[i * 12 + fh], c = fxb[j * 12 + fw];
          float rr = __builtin_amdgcn_rcpf(a + c + EPSV);
          f0[e] = (c - a) * rr;
          f1[e] = c * rr;
          if (++j == 14) { j = 0; i++; }
        }
        *(u32x2*)(lds + kt * 4096u + wb0) =
            u32x2{cvt_pk_bf16(f0[0], f0[1]), cvt_pk_bf16(f0[2], f0[3])};
        *(u32x2*)(lds + kt * 4096u + t1delta + wb1) =
            u32x2{cvt_pk_bf16(f1[0], f1[1]), cvt_pk_bf16(f1[2], f1[3])};
      }
    }
    // linear pass: fu 0..6 write lin quad t=fu (k = 392+fu*4) -> tile 12 (+1 if fu==6)
    if (fu < 7) {
      float f[4];
#pragma unroll
      for (int e = 0; e < 4; e++) {
        int t = fu * 4 + e;
        f[e] = (t < 14) ? fxb[t * 12 + fh] : fxb[(t - 14) * 12 + fw];
      }
      int g = (8 + fu * 4) & 31;          // elem offset within tile
      unsigned tile = (fu == 6) ? 13u : 12u;
      *(u32x2*)(lds + tile * 4096u + wboff(g >> 2)) =
          u32x2{cvt_pk_bf16(f[0], f[1]), cvt_pk_bf16(f[2], f[3])};
      // zero pass: tile 13 quads 1..7 (k 420..447)
      *(u32x2*)(lds + 13u * 4096u + wboff(fu + 1)) = u32x2{0u, 0u};
    }
  }
  __syncthreads();

  // =================== Layer 0 : feat(448) -> 512 (swapped operands) ===============
  {
    f32x4 acc[4][4];
#pragma unroll
    for (int ct = 0; ct < 4; ct++) {
      f32x4 bias = *(const f32x4*)(b0 + wv * 64 + ct * 16 + quad * 4);
#pragma unroll
      for (int rt = 0; rt < 4; rt++) acc[rt][ct] = bias;
    }

    // k-tile-major: wave's load for ct = ONE contiguous 1KB segment.
    const char* wb = (const char*)w0b + (unsigned)(wv * 64 + l15) * 64u + quad * 16u;
    const unsigned afb = l15 * 64u + ((quad ^ ((l15 >> 1) & 3)) * 16u);

#pragma unroll 1
    for (int kt = 0; kt < 14; kt++) {
      bf16x8 bfr[4], af[4];
#pragma unroll
      for (int ct = 0; ct < 4; ct++)
        bfr[ct] = *(const bf16x8*)(wb + ct * 1024);   // imm offsets, coalesced
#pragma unroll
      for (int rt = 0; rt < 4; rt++)
        af[rt] = *(const bf16x8*)(lds + kt * 4096u + afb + rt * 1024u);
      __builtin_amdgcn_s_setprio(1);
#pragma unroll
      for (int rt = 0; rt < 4; rt++)
#pragma unroll
        for (int ct = 0; ct < 4; ct++)
          acc[rt][ct] = __builtin_amdgcn_mfma_f32_16x16x32_bf16(bfr[ct], af[rt], acc[rt][ct], 0, 0, 0);
      __builtin_amdgcn_s_setprio(0);
      wb += 32768;   // next k-tile
    }
    __syncthreads();   // all waves done reading feat; h0 overlays it
    // epilogue: relu -> bf16 h0 at base 0 (chunk-rotate swizzle), packed b64 writes
#pragma unroll
    for (int ct = 0; ct < 4; ct++) {
      int nb = wv * 64 + ct * 16 + quad * 4;
      int kb = nb >> 3;
      unsigned off = (nb & 7) * 2;
#pragma unroll
      for (int rt = 0; rt < 4; rt++) {
        int m = rt * 16 + l15;
        f32x4 v = acc[rt][ct];
        unsigned lo = cvt_pk_bf16(fmaxf(v[0], 0.f), fmaxf(v[1], 0.f));
        unsigned hi = cvt_pk_bf16(fmaxf(v[2], 0.f), fmaxf(v[3], 0.f));
        *(u32x2*)(lds + m * 1024u + ((kb + m) & 63) * 16u + off) = u32x2{lo, hi};
      }
    }
  }
  __syncthreads();   // h0 visible

  // =================== Layer 1 : 512 -> 384 (swapped operands, barrier-free) =======
  {
    f32x4 acc[4][3];
#pragma unroll
    for (int ct = 0; ct < 3; ct++) {
      f32x4 bias = *(const f32x4*)(b1 + wv * 48 + ct * 16 + quad * 4);
#pragma unroll
      for (int rt = 0; rt < 4; rt++) acc[rt][ct] = bias;
    }

    const char* wb = (const char*)w1b + (unsigned)(wv * 48 + l15) * 64u + quad * 16u;

#pragma unroll 1
    for (int kt = 0; kt < 16; kt++) {
      bf16x8 bfr[3], af[4];
#pragma unroll
      for (int ct = 0; ct < 3; ct++)
        bfr[ct] = *(const bf16x8*)(wb + ct * 1024);
#pragma unroll
      for (int rt = 0; rt < 4; rt++) {
        int m = rt * 16 + l15;
        af[rt] = *(const bf16x8*)(lds + m * 1024u + (((kt * 4 + quad) + m) & 63) * 16u);
      }
      __builtin_amdgcn_s_setprio(1);
#pragma unroll
      for (int rt = 0; rt < 4; rt++)
#pragma unroll
        for (int ct = 0; ct < 3; ct++)
          acc[rt][ct] = __builtin_amdgcn_mfma_f32_16x16x32_bf16(bfr[ct], af[rt], acc[rt][ct], 0, 0, 0);
      __builtin_amdgcn_s_setprio(0);
      wb += 24576;
    }
    __syncthreads();   // all waves done READING h0 before h1 overwrites the region
    // epilogue -> h1 at base 0 (48 chunks/row, rotate mod 48), packed b64 writes
#pragma unroll
    for (int ct = 0; ct < 3; ct++) {
      int nb = wv * 48 + ct * 16 + quad * 4;
      int kb = nb >> 3;
      unsigned off = (nb & 7) * 2;
#pragma unroll
      for (int rt = 0; rt < 4; rt++) {
        int m = rt * 16 + l15;
        int s = kb + m;
        if (s >= 48) s -= 48;
        if (s >= 48) s -= 48;
        f32x4 v = acc[rt][ct];
        unsigned lo = cvt_pk_bf16(fmaxf(v[0], 0.f), fmaxf(v[1], 0.f));
        unsigned hi = cvt_pk_bf16(fmaxf(v[2], 0.f), fmaxf(v[3], 0.f));
        *(u32x2*)(lds + m * 768u + s * 16u + off) = u32x2{lo, hi};
      }
    }
  }
  __syncthreads();   // h1 visible

  // =================== Layer 2 : 384 -> 256, fused reduction (barrier-free) ========
  // Original operand order: lane owns col => row-reduction via 2 shfls.
  {
    f32x4 acc[4][2];
#pragma unroll
    for (int ct = 0; ct < 2; ct++) {
      float bias = b2[wv * 32 + ct * 16 + l15];
#pragma unroll
      for (int rt = 0; rt < 4; rt++) acc[rt][ct] = f32x4{bias, bias, bias, bias};
    }

    const char* wb = (const char*)w2b + (unsigned)(wv * 32 + l15) * 64u + quad * 16u;

#pragma unroll 1
    for (int kt = 0; kt < 12; kt++) {
      bf16x8 bfr[2], af[4];
#pragma unroll
      for (int ct = 0; ct < 2; ct++)
        bfr[ct] = *(const bf16x8*)(wb + ct * 1024);
#pragma unroll
      for (int rt = 0; rt < 4; rt++) {
        int m = rt * 16 + l15;
        int s = (kt * 4 + quad) + m;
        if (s >= 48) s -= 48;
        if (s >= 48) s -= 48;
        af[rt] = *(const bf16x8*)(lds + m * 768u + s * 16u);
      }
      __builtin_amdgcn_s_setprio(1);
#pragma unroll
      for (int rt = 0; rt < 4; rt++)
#pragma unroll
        for (int ct = 0; ct < 2; ct++)
          acc[rt][ct] = __builtin_amdgcn_mfma_f32_16x16x32_bf16(af[rt], bfr[ct], acc[rt][ct], 0, 0, 0);
      __builtin_amdgcn_s_setprio(0);
      wb += 16384;
    }

    // epilogue: relu(h2) * softmax-wm, reduce over rows, atomicAdd into out
#pragma unroll
    for (int ct = 0; ct < 2; ct++) {
      int col = wv * 32 + ct * 16 + l15;
      const float* wmg = wm + (col >> 4) * 144;
      float s0 = 0.f, s1 = 0.f;
#pragma unroll
      for (int rt = 0; rt < 4; rt++)
#pragma unroll
        for (int vi = 0; vi < 4; vi++) {
          int r = r0 + rt * 16 + quad * 4 + vi;
          float v = fmaxf(acc[rt][ct][vi], 0.f);
          if (r < boundary) s0 += v * wmg[r - bi0 * 144];
          else              s1 += v * wmg[r - boundary];
        }
      s0 += __shfl_xor(s0, 16); s0 += __shfl_xor(s0, 32);
      s1 += __shfl_xor(s1, 16); s1 += __shfl_xor(s1, 32);
      if (quad == 0) {
        atomicAdd(out + bi0 * 256 + col, s0);
        if (boundary < r0 + 64) atomicAdd(out + (bi0 + 1) * 256 + col, s1);
      }
    }
  }
}

extern "C" void kernel_launch(void* const* d_in, const int* in_sizes, int n_in,
                              void* d_out, int out_size, void* d_ws, size_t ws_size,
                              hipStream_t stream) {
  (void)in_sizes; (void)n_in; (void)ws_size;
  const float* x     = (const float*)d_in[0];
  const float* w0    = (const float*)d_in[1];
  const float* b0    = (const float*)d_in[2];
  const float* w1    = (const float*)d_in[3];
  const float* b1    = (const float*)d_in[4];
  const float* w2    = (const float*)d_in[5];
  const float* b2    = (const float*)d_in[6];
  const float* wmask = (const float*)d_in[7];
  float* out = (float*)d_out;
  char* ws = (char*)d_ws;
  float* wm = (float*)ws;                                        // 16*144*4 = 9216
  unsigned short* w0b = (unsigned short*)(ws + 9216);            // 512*448*2 = 458752
  unsigned short* w1b = (unsigned short*)(ws + 9216 + 458752);   // 384*512*2 = 393216
  unsigned short* w2b = (unsigned short*)(ws + 9216 + 458752 + 393216);  // 256*384*2

  prep_conv<<<2052, 256, 0, stream>>>(w0, w1, w2, w0b, w1b, w2b, wmask, wm, out);
  fused_main<<<2304, 512, 0, stream>>>(x, b0, b1, b2, w0b, w1b, w2b, wm, out);
}